// Round 10
// baseline (770.419 us; speedup 1.0000x reference)
//
#include <hip/hip_runtime.h>
#include <hip/hip_fp16.h>
#include <cmath>

#define NN 20000
#define EE 500000
#define GG 64
#define TS 8192
#define SW 4096   // edge-balanced wave count (per stats kernel)
#define EPS 1e-5f
#define LOG2E 1.442695040888963f
#define LN2 0.693147180559945f

typedef unsigned long long u64a __attribute__((aligned(4)));
typedef _Float16 f16x8 __attribute__((ext_vector_type(8)));
typedef float f32x4 __attribute__((ext_vector_type(4)));
typedef float f32x2 __attribute__((ext_vector_type(2)));

__device__ __forceinline__ float softplus_ref(float x) {
    return fmaxf(x, 0.f) + log1pf(__expf(-fabsf(x)));
}

// gaussian table: g[s][k] = exp(coeff*(d_s - o_k)^2)
__global__ void k_gtab(float* __restrict__ g) {
    int i = blockIdx.x * 256 + threadIdx.x;
    if (i >= TS * 100) return;
    int s = i / 100, k = i - 100 * s;
    float d = s * (6.0f / (TS - 1.0f));
    float o = k * (6.0f / 99.0f);
    float step = 6.0f / 99.0f;
    float coeff = -0.5f / (step * step);
    float df = d - o;
    g[i] = __expf(coeff * df * df);
}

// Nearest-neighbor table, paired channels: Tn[l][s][t] = half2(T[c=t], T[c=t+64])
// fp8 copy Tn8 (x16-scaled, HW pk encode): row = 64 ushort = 128 B = one line.
__global__ void __launch_bounds__(256) k_build_T(
    const float* __restrict__ g, const float* __restrict__ convW,
    const float* __restrict__ convB, __half2* __restrict__ Tn,
    unsigned short* __restrict__ Tn8) {
    int lane = threadIdx.x & 63;
    int wv = __builtin_amdgcn_readfirstlane(threadIdx.x >> 6);
    int l = blockIdx.y;
    int s0 = blockIdx.x * 16 + wv * 4;
    const float* w = convW + ((size_t)l * 228 + 128) * 128;
    const float* g0 = g + (size_t)s0 * 100;
    float b0 = convB[l * 128 + lane], b1 = convB[l * 128 + lane + 64];
    float2 a0 = {b0, b1}, a1 = {b0, b1}, a2 = {b0, b1}, a3 = {b0, b1};
#pragma unroll 4
    for (int k = 0; k < 100; k++) {
        float w0 = w[k * 128 + lane];
        float w1 = w[k * 128 + lane + 64];
        float ga = g0[k], gb = g0[100 + k], gc = g0[200 + k], gd = g0[300 + k];
        a0.x += ga * w0; a0.y += ga * w1;
        a1.x += gb * w0; a1.y += gb * w1;
        a2.x += gc * w0; a2.y += gc * w1;
        a3.x += gd * w0; a3.y += gd * w1;
    }
    Tn[((size_t)l * TS + s0 + 0) * 64 + lane] = __floats2half2_rn(a0.x, a0.y);
    Tn[((size_t)l * TS + s0 + 1) * 64 + lane] = __floats2half2_rn(a1.x, a1.y);
    Tn[((size_t)l * TS + s0 + 2) * 64 + lane] = __floats2half2_rn(a2.x, a2.y);
    Tn[((size_t)l * TS + s0 + 3) * 64 + lane] = __floats2half2_rn(a3.x, a3.y);
    int e0 = __builtin_amdgcn_cvt_pk_fp8_f32(16.f * a0.x, 16.f * a0.y, 0, false);
    int e1 = __builtin_amdgcn_cvt_pk_fp8_f32(16.f * a1.x, 16.f * a1.y, 0, false);
    int e2 = __builtin_amdgcn_cvt_pk_fp8_f32(16.f * a2.x, 16.f * a2.y, 0, false);
    int e3 = __builtin_amdgcn_cvt_pk_fp8_f32(16.f * a3.x, 16.f * a3.y, 0, false);
    Tn8[((size_t)l * TS + s0 + 0) * 64 + lane] = (unsigned short)(e0 & 0xffff);
    Tn8[((size_t)l * TS + s0 + 1) * 64 + lane] = (unsigned short)(e1 & 0xffff);
    Tn8[((size_t)l * TS + s0 + 2) * 64 + lane] = (unsigned short)(e2 & 0xffff);
    Tn8[((size_t)l * TS + s0 + 3) * 64 + lane] = (unsigned short)(e3 & 0xffff);
}

// W fragments for mfma_f32_16x16x32_f16, B operand, output-col permuted so the
// natural store order IS the (c, c+64) pair layout of uph/vph.
__global__ void k_prepW2(const float* __restrict__ convW, _Float16* __restrict__ Wf) {
    int lane = threadIdx.x;   // 64
    int ct = blockIdx.x;      // 16
    int half = blockIdx.y;    // 2
    int l = blockIdx.z;       // 6
    int p = ct * 16 + (lane & 15);
    int s = p >> 7;           // 0 = u block (W rows 0..63), 1 = v block (rows 64..127)
    int r = p & 127;
    int colW = (r >> 1) + (r & 1) * 64;
    int k0 = half * 32 + (lane >> 4) * 8;
    _Float16* dst = Wf + (((size_t)(l * 16 + ct) * 2 + half) * 64 + lane) * 8;
#pragma unroll
    for (int i = 0; i < 8; i++) {
        float v = convW[((size_t)l * 228 + s * 64 + k0 + i) * 128 + colW];
        dst[i] = (_Float16)v;
    }
}

__global__ void k_embed(const int* __restrict__ an, const float* __restrict__ emb,
                        const float* __restrict__ W, const float* __restrict__ b,
                        float* __restrict__ x, _Float16* __restrict__ xh) {
    int c = threadIdx.x & 63, nl = threadIdx.x >> 6;
    int n = blockIdx.x * 4 + nl;
    if (n >= NN) return;
    const float* e = emb + (size_t)an[n] * 92;
    float acc = b[c];
#pragma unroll 4
    for (int k = 0; k < 92; k++) acc += e[k] * W[k * 64 + c];
    x[(size_t)n * 64 + c] = acc;
    xh[(size_t)n * 64 + c] = (_Float16)acc;
}

__global__ void k_hist(const int* __restrict__ dst, int* __restrict__ counts) {
    int e = blockIdx.x * 256 + threadIdx.x;
    if (e < EE) atomicAdd(&counts[dst[e]], 1);
}

__global__ void k_scan_local(const int* __restrict__ counts, int* __restrict__ rp,
                             int* __restrict__ bsum) {
    __shared__ int buf[1024];
    int b = blockIdx.x, tid = threadIdx.x;
    int i = b * 1024 + tid;
    int val = (i < NN) ? counts[i] : 0;
    buf[tid] = val;
    __syncthreads();
    for (int off = 1; off < 1024; off <<= 1) {
        int t = (tid >= off) ? buf[tid - off] : 0;
        __syncthreads();
        buf[tid] += t;
        __syncthreads();
    }
    if (i < NN) rp[i + 1] = buf[tid];
    if (tid == 1023) bsum[b] = buf[1023];
}

__global__ void k_scan_off(int* __restrict__ bsum, int nb) {
    if (threadIdx.x == 0) {
        int acc = 0;
        for (int b = 0; b < nb; b++) { int v = bsum[b]; bsum[b] = acc; acc += v; }
    }
}

__global__ void k_scan_add(int* __restrict__ rp, const int* __restrict__ bsum) {
    int b = blockIdx.x, tid = threadIdx.x;
    int i = b * 1024 + tid;
    if (i < NN) rp[i + 1] += bsum[b];
    if (b == 0 && tid == 0) rp[0] = 0;
}

// wave -> start node for edge-balanced stats kernels
__global__ void k_wsn(const int* __restrict__ rp, int* __restrict__ wsn) {
    int w = blockIdx.x * 256 + threadIdx.x;
    if (w >= SW) return;
    int e0 = (int)((long long)w * EE / SW);
    int lo = 0, hi = NN;
    while (lo + 1 < hi) {
        int mid = (lo + hi) >> 1;
        if (rp[mid] <= e0) lo = mid; else hi = mid;
    }
    wsn[w] = lo;
}

// scatter + pack fused: ej[pos] = (src<<13) | j  (dst-sorted order)
__global__ void k_scatter(const int* __restrict__ src, const int* __restrict__ dst,
                          const float* __restrict__ dist, const int* __restrict__ rp,
                          int* __restrict__ cursor, unsigned* __restrict__ ej) {
    int e = blockIdx.x * 256 + threadIdx.x;
    if (e < EE) {
        int d = dst[e];
        int p = atomicAdd(&cursor[d], 1);
        float t = dist[e] * ((TS - 1.0f) / 6.0f);
        int j = (int)(t + 0.5f);
        if (j > TS - 1) j = TS - 1;
        ej[rp[d] + p] = ((unsigned)src[e] << 13) | (unsigned)j;
    }
}

// u,v via MFMA (layer 0): [20000x64]x[64x256] fp16 GEMM, fp32 accum.
__global__ void __launch_bounds__(256) k_uvmm(
    const _Float16* __restrict__ xh, const _Float16* __restrict__ Wf, int l,
    _Float16* __restrict__ uph, _Float16* __restrict__ vph) {
    int lane = threadIdx.x & 63;
    int wv = threadIdx.x >> 6;
    int tile = blockIdx.x * 4 + wv;
    if (tile >= NN / 16) return;
    int node = tile * 16 + (lane & 15);
    const f16x8* ax = (const f16x8*)(xh + (size_t)node * 64 + ((lane >> 4) * 8));
    f16x8 a0 = ax[0];   // k 0..31 slice
    f16x8 a1 = ax[4];   // k 32..63 slice
    const f16x8* wf = (const f16x8*)Wf + (size_t)l * 16 * 2 * 64;
    int rowb = tile * 16 + ((lane >> 4) << 2);
#pragma unroll
    for (int ct = 0; ct < 16; ct++) {
        f16x8 b0 = wf[(ct * 2 + 0) * 64 + lane];
        f16x8 b1 = wf[(ct * 2 + 1) * 64 + lane];
        f32x4 acc = {0.f, 0.f, 0.f, 0.f};
        acc = __builtin_amdgcn_mfma_f32_16x16x32_f16(a0, b0, acc, 0, 0, 0);
        acc = __builtin_amdgcn_mfma_f32_16x16x32_f16(a1, b1, acc, 0, 0, 0);
        int p = ct * 16 + (lane & 15);
        _Float16* dst = (p < 128) ? (uph + p) : (vph + (p - 128));
#pragma unroll
        for (int r2 = 0; r2 < 4; r2++)
            dst[(size_t)(rowb + r2) * 128] = (_Float16)acc[r2];
    }
}

// Fused LN(prev)+residual+softplus in fragment layout, then MFMA u,v (layers 1..5).
// Lane holds 16 of its node's 64 channels: k in [ks,ks+8) and [32+ks,32+ks+8), ks=(lane>>4)*8.
__global__ void __launch_bounds__(256) k_uvln2(
    const float* __restrict__ accb, const float* __restrict__ lng,
    const float* __restrict__ lnb, int lp,
    const float* __restrict__ xin, float* __restrict__ xout,
    const _Float16* __restrict__ Wf, int l,
    _Float16* __restrict__ uph, _Float16* __restrict__ vph) {
    int lane = threadIdx.x & 63;
    int wv = threadIdx.x >> 6;
    int tile = blockIdx.x * 4 + wv;
    if (tile >= NN / 16) return;
    int node = tile * 16 + (lane & 15);
    int ks = (lane >> 4) * 8;
    const float* ab = accb + (size_t)node * 64;
    const float* xb = xin + (size_t)node * 64;
    float av[16], xr[16];
#pragma unroll
    for (int i = 0; i < 8; i++) { av[i] = ab[ks + i]; av[8 + i] = ab[32 + ks + i]; }
#pragma unroll
    for (int i = 0; i < 8; i++) { xr[i] = xb[ks + i]; xr[8 + i] = xb[32 + ks + i]; }
    float s = 0.f;
#pragma unroll
    for (int i = 0; i < 16; i++) s += av[i];
    s += __shfl_xor(s, 16, 64);
    s += __shfl_xor(s, 32, 64);
    float mean = s * (1.0f / 64.0f);
    float vv = 0.f;
#pragma unroll
    for (int i = 0; i < 16; i++) { float d = av[i] - mean; vv += d * d; }
    vv += __shfl_xor(vv, 16, 64);
    vv += __shfl_xor(vv, 32, 64);
    float rs = rsqrtf(vv * (1.0f / 64.0f) + EPS);
    const float* lg = lng + lp * 64;
    const float* lb = lnb + lp * 64;
    f16x8 a0, a1;
    float* xo = xout + (size_t)node * 64;
#pragma unroll
    for (int i = 0; i < 8; i++) {
        float h = (av[i] - mean) * rs * lg[ks + i] + lb[ks + i];
        float o = softplus_ref(h + xr[i]);
        xo[ks + i] = o;
        a0[i] = (_Float16)o;
    }
#pragma unroll
    for (int i = 0; i < 8; i++) {
        float h = (av[8 + i] - mean) * rs * lg[32 + ks + i] + lb[32 + ks + i];
        float o = softplus_ref(h + xr[8 + i]);
        xo[32 + ks + i] = o;
        a1[i] = (_Float16)o;
    }
    const f16x8* wf = (const f16x8*)Wf + (size_t)l * 16 * 2 * 64;
    int rowb = tile * 16 + ((lane >> 4) << 2);
#pragma unroll
    for (int ct = 0; ct < 16; ct++) {
        f16x8 b0 = wf[(ct * 2 + 0) * 64 + lane];
        f16x8 b1 = wf[(ct * 2 + 1) * 64 + lane];
        f32x4 acc = {0.f, 0.f, 0.f, 0.f};
        acc = __builtin_amdgcn_mfma_f32_16x16x32_f16(a0, b0, acc, 0, 0, 0);
        acc = __builtin_amdgcn_mfma_f32_16x16x32_f16(a1, b1, acc, 0, 0, 0);
        int p = ct * 16 + (lane & 15);
        _Float16* dst = (p < 128) ? (uph + p) : (vph + (p - 128));
#pragma unroll
        for (int r2 = 0; r2 < 4; r2++)
            dst[(size_t)(rowb + r2) * 128] = (_Float16)acc[r2];
    }
}

// v -> fp8 (x16, HW pk encode): vp8 uint i covers fp16 positions 4i..4i+3
__global__ void k_v8(const _Float16* __restrict__ vph, unsigned* __restrict__ vp8) {
    int i = blockIdx.x * 256 + threadIdx.x;
    if (i >= NN * 32) return;
    uint2 hv = *(const uint2*)(vph + (size_t)i * 4);
    float2 f0 = __half22float2(*(const __half2*)&hv.x);
    float2 f1 = __half22float2(*(const __half2*)&hv.y);
    int b = __builtin_amdgcn_cvt_pk_fp8_f32(16.f * f0.x, 16.f * f0.y, 0, false);
    b = __builtin_amdgcn_cvt_pk_fp8_f32(16.f * f1.x, 16.f * f1.y, b, true);
    vp8[i] = (unsigned)b;
}

// ---------------- fp16 half-row gather machinery (unchanged) ----------------
#define GRP2(P, BODY)                                                        \
    {                                                                        \
        unsigned e[P];                                                       \
        _Pragma("unroll")                                                    \
        for (int t = 0; t < P; t++) {                                        \
            unsigned long long ep = *(const u64a*)&ej[idx + 2 * t];          \
            e[t] = slot ? (unsigned)(ep >> 32) : (unsigned)ep;               \
        }                                                                    \
        __half2 vh[P], th[P];                                                \
        _Pragma("unroll")                                                    \
        for (int t = 0; t < P; t++) {                                        \
            vh[t] = vp[(size_t)(e[t] >> 13) * 64 + hp];                      \
            th[t] = Tn[(size_t)(e[t] & 8191u) * 64 + hp];                    \
        }                                                                    \
        _Pragma("unroll")                                                    \
        for (int t = 0; t < P; t++) { BODY }                                 \
    }

#define STATS_BODY                                                           \
    float2 vv = __half22float2(vh[t]);                                       \
    float2 tt = __half22float2(th[t]);                                       \
    float z0 = uu.x + vv.x + tt.x;                                           \
    float z1 = uu.y + vv.y + tt.y;                                           \
    sx += z0; qx += z0 * z0; sy += z1; qy += z1 * z1;

#define AGG_BODY                                                             \
    __half2 vt = __hadd2(vh[t], th[t]);                                      \
    float2 f = __half22float2(vt);                                           \
    float z0 = fmaf(A1, f.x, C1);                                            \
    float z1 = fmaf(A2, f.y, C2);                                            \
    float sg = __builtin_amdgcn_rcpf(1.0f + __builtin_amdgcn_exp2f(-z0));    \
    float sp = fmaxf(z1, 0.f) +                                              \
               __builtin_amdgcn_logf(1.0f + __builtin_amdgcn_exp2f(-fabsf(z1))); \
    acc += sg * sp;

// pass A (fp16): BN stats; channel-half pinned to XCD group via blockIdx%8.
__global__ void __launch_bounds__(256) k_stats_h(
    const __half2* __restrict__ up, const __half2* __restrict__ vp,
    const __half2* __restrict__ Tn, const unsigned* __restrict__ ej,
    const int* __restrict__ rp, const int* __restrict__ wsn,
    float* __restrict__ sums) {
    int lane = threadIdx.x & 63;
    int wv = __builtin_amdgcn_readfirstlane(threadIdx.x >> 6);
    int bid = blockIdx.x;
    int h = (bid >> 2) & 1;
    int r = ((bid >> 3) << 2) | (bid & 3);
    int slot = lane >> 5;
    int hp = h * 32 + (lane & 31);
    int w = r * 4 + wv;
    int e0 = (int)((long long)w * EE / SW);
    int e1 = (int)((long long)(w + 1) * EE / SW);
    int n = __builtin_amdgcn_readfirstlane(wsn[w]);
    int rend = __builtin_amdgcn_readfirstlane(rp[n + 1]);
    float sx = 0.f, sy = 0.f, qx = 0.f, qy = 0.f;
    int idx = e0;
    while (idx < e1) {
        while (idx >= rend) {
            ++n;
            rend = __builtin_amdgcn_readfirstlane(rp[n + 1]);
        }
        float2 uu = __half22float2(up[(size_t)n * 64 + hp]);
        int stop = (e1 < rend) ? e1 : rend;
        for (; idx + 16 <= stop; idx += 16) GRP2(8, STATS_BODY)
        if (idx + 8 <= stop) { GRP2(4, STATS_BODY) idx += 8; }
        if (idx + 4 <= stop) { GRP2(2, STATS_BODY) idx += 4; }
        if (idx + 2 <= stop) { GRP2(1, STATS_BODY) idx += 2; }
        if (idx < stop) {
            unsigned e = ej[idx];
            __half2 vh0 = vp[(size_t)(e >> 13) * 64 + hp];
            __half2 th0 = Tn[(size_t)(e & 8191u) * 64 + hp];
            float2 vv = __half22float2(vh0);
            float2 tt = __half22float2(th0);
            float z0 = uu.x + vv.x + tt.x;
            float z1 = uu.y + vv.y + tt.y;
            if (!slot) {
                sx += z0; qx += z0 * z0; sy += z1; qy += z1 * z1;
            }
            idx += 1;
        }
    }
    sx += __shfl_xor(sx, 32, 64); sy += __shfl_xor(sy, 32, 64);
    qx += __shfl_xor(qx, 32, 64); qy += __shfl_xor(qy, 32, 64);
    __shared__ float red[4][32][4];
    if (!slot) {
        float* rr = red[wv][lane & 31];
        rr[0] = sx; rr[1] = sy; rr[2] = qx; rr[3] = qy;
    }
    __syncthreads();
    if (wv == 0 && !slot) {
        for (int q = 1; q < 4; q++) {
            const float* rr = red[q][lane & 31];
            sx += rr[0]; sy += rr[1]; qx += rr[2]; qy += rr[3];
        }
        int c0 = hp;
        atomicAdd(&sums[c0], sx);
        atomicAdd(&sums[64 + c0], sy);
        atomicAdd(&sums[128 + c0], qx);
        atomicAdd(&sums[192 + c0], qy);
    }
}

// pass A (fp8, HW decode): full rows, 1 line/table/edge, 2 edges/instr.
#define SGRP8B(P)                                                            \
    {                                                                        \
        unsigned e[P];                                                       \
        _Pragma("unroll")                                                    \
        for (int t = 0; t < P; t++) {                                        \
            unsigned long long ep = *(const u64a*)&ej[idx + 2 * t];          \
            e[t] = slot ? (unsigned)(ep >> 32) : (unsigned)ep;               \
        }                                                                    \
        unsigned vr[P], tr[P];                                               \
        _Pragma("unroll")                                                    \
        for (int t = 0; t < P; t++) {                                        \
            vr[t] = vq8[(size_t)(e[t] >> 13) * 32 + q];                      \
            tr[t] = tq8[(size_t)(e[t] & 8191u) * 32 + q];                    \
        }                                                                    \
        _Pragma("unroll")                                                    \
        for (int t = 0; t < P; t++) {                                        \
            f32x2 v0 = __builtin_amdgcn_cvt_pk_f32_fp8(vr[t], false);        \
            f32x2 v1 = __builtin_amdgcn_cvt_pk_f32_fp8(vr[t], true);         \
            f32x2 t0 = __builtin_amdgcn_cvt_pk_f32_fp8(tr[t], false);        \
            f32x2 t1 = __builtin_amdgcn_cvt_pk_f32_fp8(tr[t], true);         \
            float z0a = u0 + v0[0] + t0[0], z1a = u1 + v0[1] + t0[1];        \
            float z0b = u2 + v1[0] + t1[0], z1b = u3 + v1[1] + t1[1];        \
            sza += z0a; qza += z0a * z0a; sya += z1a; qya += z1a * z1a;      \
            szb += z0b; qzb += z0b * z0b; syb += z1b; qyb += z1b * z1b;      \
        }                                                                    \
    }

__global__ void __launch_bounds__(256) k_stats8b(
    const __half2* __restrict__ up, const unsigned* __restrict__ vq8,
    const unsigned* __restrict__ tq8, const unsigned* __restrict__ ej,
    const int* __restrict__ rp, const int* __restrict__ wsn,
    float* __restrict__ sums) {
    int lane = threadIdx.x & 63;
    int wv = __builtin_amdgcn_readfirstlane(threadIdx.x >> 6);
    int slot = lane >> 5, q = lane & 31;
    int w = blockIdx.x * 4 + wv;
    int e0 = (int)((long long)w * EE / SW);
    int e1 = (int)((long long)(w + 1) * EE / SW);
    int n = __builtin_amdgcn_readfirstlane(wsn[w]);
    int rend = __builtin_amdgcn_readfirstlane(rp[n + 1]);
    float sza = 0, szb = 0, sya = 0, syb = 0;
    float qza = 0, qzb = 0, qya = 0, qyb = 0;
    float u0 = 0, u1 = 0, u2 = 0, u3 = 0;
    int idx = e0;
    while (idx < e1) {
        while (idx >= rend) {
            ++n;
            rend = __builtin_amdgcn_readfirstlane(rp[n + 1]);
        }
        {
            uint2 uw = *(const uint2*)&up[(size_t)n * 64 + 2 * q];
            float2 fa = __half22float2(*(const __half2*)&uw.x);
            float2 fb = __half22float2(*(const __half2*)&uw.y);
            u0 = 16.0f * fa.x; u1 = 16.0f * fa.y;
            u2 = 16.0f * fb.x; u3 = 16.0f * fb.y;
        }
        int stop = (e1 < rend) ? e1 : rend;
        for (; idx + 16 <= stop; idx += 16) SGRP8B(8)
        if (idx + 8 <= stop) { SGRP8B(4) idx += 8; }
        if (idx + 4 <= stop) { SGRP8B(2) idx += 4; }
        if (idx + 2 <= stop) { SGRP8B(1) idx += 2; }
        if (idx < stop) {
            unsigned e = ej[idx];
            unsigned vr = vq8[(size_t)(e >> 13) * 32 + q];
            unsigned tr = tq8[(size_t)(e & 8191u) * 32 + q];
            f32x2 v0 = __builtin_amdgcn_cvt_pk_f32_fp8(vr, false);
            f32x2 v1 = __builtin_amdgcn_cvt_pk_f32_fp8(vr, true);
            f32x2 t0 = __builtin_amdgcn_cvt_pk_f32_fp8(tr, false);
            f32x2 t1 = __builtin_amdgcn_cvt_pk_f32_fp8(tr, true);
            float z0a = u0 + v0[0] + t0[0], z1a = u1 + v0[1] + t0[1];
            float z0b = u2 + v1[0] + t1[0], z1b = u3 + v1[1] + t1[1];
            if (!slot) {
                sza += z0a; qza += z0a * z0a; sya += z1a; qya += z1a * z1a;
                szb += z0b; qzb += z0b * z0b; syb += z1b; qyb += z1b * z1b;
            }
            idx += 1;
        }
    }
    sza += __shfl_xor(sza, 32, 64); szb += __shfl_xor(szb, 32, 64);
    sya += __shfl_xor(sya, 32, 64); syb += __shfl_xor(syb, 32, 64);
    qza += __shfl_xor(qza, 32, 64); qzb += __shfl_xor(qzb, 32, 64);
    qya += __shfl_xor(qya, 32, 64); qyb += __shfl_xor(qyb, 32, 64);
    __shared__ float red[4][32][8];
    if (!slot) {
        float* rr = red[wv][q];
        rr[0] = sza; rr[1] = szb; rr[2] = sya; rr[3] = syb;
        rr[4] = qza; rr[5] = qzb; rr[6] = qya; rr[7] = qyb;
    }
    __syncthreads();
    if (wv == 0 && !slot) {
        for (int r = 1; r < 4; r++) {
            const float* rr = red[r][q];
            sza += rr[0]; szb += rr[1]; sya += rr[2]; syb += rr[3];
            qza += rr[4]; qzb += rr[5]; qya += rr[6]; qyb += rr[7];
        }
        int cA = 2 * q, cB = 2 * q + 1;
        const float s1 = 1.0f / 16.0f, s2 = 1.0f / 256.0f;
        atomicAdd(&sums[cA], sza * s1);        atomicAdd(&sums[cB], szb * s1);
        atomicAdd(&sums[64 + cA], sya * s1);   atomicAdd(&sums[64 + cB], syb * s1);
        atomicAdd(&sums[128 + cA], qza * s2);  atomicAdd(&sums[128 + cB], qzb * s2);
        atomicAdd(&sums[192 + cA], qya * s2);  atomicAdd(&sums[192 + cB], qyb * s2);
    }
}

// pass B: half-channel aggregate; writes partial acc (no LN here).
__global__ void __launch_bounds__(256) k_aggh(
    const __half2* __restrict__ up, const __half2* __restrict__ vp,
    const __half2* __restrict__ Tn, const unsigned* __restrict__ ej,
    const int* __restrict__ rp, const float* __restrict__ sums,
    const float* __restrict__ bng, const float* __restrict__ bnb,
    int l, float* __restrict__ accbuf) {
    int lane = threadIdx.x & 63;
    int wv = __builtin_amdgcn_readfirstlane(threadIdx.x >> 6);
    int bid = blockIdx.x;
    int h = (bid >> 2) & 1;
    int r = ((bid >> 3) << 2) | (bid & 3);
    int slot = lane >> 5;
    int hp = h * 32 + (lane & 31);
    int i = r * 4 + wv;

    int c0 = hp;
    float mu1 = sums[c0] * (1.0f / EE);
    float var1 = sums[128 + c0] * (1.0f / EE) - mu1 * mu1;
    float A1 = rsqrtf(var1 + EPS) * bng[l * 128 + c0];
    float B1 = bnb[l * 128 + c0] - mu1 * A1;
    float mu2 = sums[64 + c0] * (1.0f / EE);
    float var2 = sums[192 + c0] * (1.0f / EE) - mu2 * mu2;
    float A2 = rsqrtf(var2 + EPS) * bng[l * 128 + 64 + c0];
    float B2 = bnb[l * 128 + 64 + c0] - mu2 * A2;

    float2 uu = __half22float2(up[(size_t)i * 64 + hp]);
    float C1 = fmaf(A1, uu.x, B1) * LOG2E;
    float C2 = fmaf(A2, uu.y, B2) * LOG2E;
    A1 *= LOG2E; A2 *= LOG2E;
    float acc = 0.f;
    int rs = __builtin_amdgcn_readfirstlane(rp[i]);
    int re = __builtin_amdgcn_readfirstlane(rp[i + 1]);
    int idx = rs;
    for (; idx + 16 <= re; idx += 16) GRP2(8, AGG_BODY)
    if (idx + 8 <= re) { GRP2(4, AGG_BODY) idx += 8; }
    if (idx + 4 <= re) { GRP2(2, AGG_BODY) idx += 4; }
    if (idx + 2 <= re) { GRP2(1, AGG_BODY) idx += 2; }
    if (idx < re) {
        unsigned e = ej[idx];
        __half2 vh0 = vp[(size_t)(e >> 13) * 64 + hp];
        __half2 th0 = Tn[(size_t)(e & 8191u) * 64 + hp];
        __half2 vt = __hadd2(vh0, th0);
        float2 f = __half22float2(vt);
        float z0 = fmaf(A1, f.x, C1);
        float z1 = fmaf(A2, f.y, C2);
        float sg = __builtin_amdgcn_rcpf(1.0f + __builtin_amdgcn_exp2f(-z0));
        float sp = fmaxf(z1, 0.f) +
                   __builtin_amdgcn_logf(1.0f + __builtin_amdgcn_exp2f(-fabsf(z1)));
        if (!slot) acc += sg * sp;
    }
    acc += __shfl_xor(acc, 32, 64);
    if (!slot) accbuf[(size_t)i * 64 + hp] = acc * LN2;
}

// final-layer LN + residual + softplus epilogue
__global__ void __launch_bounds__(256) k_lnfin(
    const float* __restrict__ accbuf,
    const float* __restrict__ lng, const float* __restrict__ lnb,
    int l, const float* __restrict__ xin, float* __restrict__ xout) {
    int lane = threadIdx.x & 63;
    int wv = __builtin_amdgcn_readfirstlane(threadIdx.x >> 6);
    int i = blockIdx.x * 4 + wv;
    float a = accbuf[(size_t)i * 64 + lane];
    float xr = xin[(size_t)i * 64 + lane];
    float s = a;
#pragma unroll
    for (int off = 32; off; off >>= 1) s += __shfl_xor(s, off, 64);
    float mean = s * (1.0f / 64.0f);
    float e0v = a - mean;
    float vv2 = e0v * e0v;
#pragma unroll
    for (int off = 32; off; off >>= 1) vv2 += __shfl_xor(vv2, off, 64);
    float var = vv2 * (1.0f / 64.0f);
    float h = e0v * rsqrtf(var + EPS) * lng[l * 64 + lane] + lnb[l * 64 + lane];
    xout[(size_t)i * 64 + lane] = softplus_ref(h + xr);
}

// batch sorted -> graph row pointers by binary search
__global__ void k_gp(const int* __restrict__ batch, int* __restrict__ gp) {
    int g = threadIdx.x;
    if (g > GG) return;
    int lo = 0, hi = NN;
    while (lo < hi) {
        int mid = (lo + hi) >> 1;
        if (batch[mid] < g) lo = mid + 1; else hi = mid;
    }
    gp[g] = lo;
}

// atomic-free segmented mean-pool
__global__ void k_pool2(const float* __restrict__ x, const int* __restrict__ gp,
                        float* __restrict__ mols) {
    int g = blockIdx.x;
    int lane = threadIdx.x & 63, slot = threadIdx.x >> 6;
    int s0 = gp[g], s1 = gp[g + 1];
    float acc = 0.f;
    for (int n = s0 + slot; n < s1; n += 4) acc += x[(size_t)n * 64 + lane];
    __shared__ float red[4][64];
    red[slot][lane] = acc;
    __syncthreads();
    if (slot == 0) {
        float a = red[0][lane] + red[1][lane] + red[2][lane] + red[3][lane];
        float cc = fmaxf((float)(s1 - s0), 1.0f);
        mols[g * 64 + lane] = a / cc;
    }
}

__global__ void k_mlp(const float* __restrict__ mols,
                      const float* __restrict__ fc1W, const float* __restrict__ fc1b,
                      const float* __restrict__ fcsW, const float* __restrict__ fcsb,
                      const float* __restrict__ outW, const float* __restrict__ outb,
                      float* __restrict__ y) {
    int g = blockIdx.x, t = threadIdx.x; // 128 threads
    __shared__ float m[64];
    __shared__ float h[128];
    __shared__ float rbuf[128];
    if (t < 64) m[t] = mols[g * 64 + t];
    __syncthreads();
    float a = fc1b[t];
#pragma unroll 16
    for (int k = 0; k < 64; k++) a += m[k] * fc1W[k * 128 + t];
    h[t] = softplus_ref(a);
    __syncthreads();
    for (int i = 0; i < 3; i++) {
        float b = fcsb[i * 128 + t];
#pragma unroll 16
        for (int k = 0; k < 128; k++) b += h[k] * fcsW[((size_t)i * 128 + k) * 128 + t];
        __syncthreads();
        h[t] = softplus_ref(b);
        __syncthreads();
    }
    rbuf[t] = h[t] * outW[t];
    __syncthreads();
    if (t < 64) {
        float s2 = rbuf[t] + rbuf[t + 64];
#pragma unroll
        for (int off = 32; off; off >>= 1) s2 += __shfl_xor(s2, off, 64);
        if (t == 0) y[g] = s2 + outb[0];
    }
}

extern "C" void kernel_launch(void* const* d_in, const int* in_sizes, int n_in,
                              void* d_out, int out_size, void* d_ws, size_t ws_size,
                              hipStream_t stream) {
    const int*   an    = (const int*)d_in[0];
    const int*   nbr   = (const int*)d_in[1];
    const float* dist  = (const float*)d_in[2];
    const int*   batch = (const int*)d_in[3];
    const float* emb   = (const float*)d_in[4];
    const float* nucW  = (const float*)d_in[5];
    const float* nucB  = (const float*)d_in[6];
    const float* convW = (const float*)d_in[7];
    const float* convB = (const float*)d_in[8];
    const float* bng   = (const float*)d_in[9];
    const float* bnb   = (const float*)d_in[10];
    const float* lng   = (const float*)d_in[11];
    const float* lnb   = (const float*)d_in[12];
    const float* fc1W  = (const float*)d_in[13];
    const float* fc1b  = (const float*)d_in[14];
    const float* fcsW  = (const float*)d_in[15];
    const float* fcsb  = (const float*)d_in[16];
    const float* outW  = (const float*)d_in[17];
    const float* outb  = (const float*)d_in[18];
    const int* srcI = nbr;
    const int* dstI = nbr + EE;

    char* base = (char*)d_ws;
    size_t off = 0;
    auto alloc = [&](size_t b) { size_t r = off; off += (b + 255) & ~(size_t)255; return r; };
    float*          gtab   = (float*)(base + alloc((size_t)TS * 100 * 4));
    __half2*        Tall   = (__half2*)(base + alloc((size_t)6 * TS * 64 * 4));
    unsigned short* Tall8  = (unsigned short*)(base + alloc((size_t)6 * TS * 64 * 2));
    _Float16*       Wf     = (_Float16*)(base + alloc((size_t)6 * 16 * 2 * 64 * 8 * 2));
    float*          x0     = (float*)(base + alloc((size_t)NN * 64 * 4));
    float*          x1     = (float*)(base + alloc((size_t)NN * 64 * 4));
    _Float16*       xh     = (_Float16*)(base + alloc((size_t)NN * 64 * 2));
    _Float16*       uph    = (_Float16*)(base + alloc((size_t)NN * 128 * 2));
    _Float16*       vph    = (_Float16*)(base + alloc((size_t)NN * 128 * 2));
    unsigned*       vp8    = (unsigned*)(base + alloc((size_t)NN * 32 * 4));
    float*          accb   = (float*)(base + alloc((size_t)NN * 64 * 4));
    float*          sums6  = (float*)(base + alloc((size_t)6 * 256 * 4));
    int*            counts = (int*)(base + alloc((size_t)NN * 4));
    int*            cursor = (int*)(base + alloc((size_t)NN * 4));
    int*            rp     = (int*)(base + alloc((size_t)(NN + 1) * 4));
    int*            bsum   = (int*)(base + alloc(64 * 4));
    unsigned*       ej     = (unsigned*)(base + alloc((size_t)(EE + 64) * 4));
    int*            wsn    = (int*)(base + alloc((size_t)SW * 4));
    float*          mols   = (float*)(base + alloc((size_t)GG * 64 * 4));
    int*            gp     = (int*)(base + alloc((size_t)(GG + 1) * 4));

    hipMemsetAsync(counts, 0, (size_t)NN * 4, stream);
    hipMemsetAsync(cursor, 0, (size_t)NN * 4, stream);
    hipMemsetAsync(sums6, 0, (size_t)6 * 256 * 4, stream);

    k_gtab<<<(TS * 100 + 255) / 256, 256, 0, stream>>>(gtab);
    k_build_T<<<dim3(TS / 16, 6), 256, 0, stream>>>(gtab, convW, convB, Tall, Tall8);
    k_prepW2<<<dim3(16, 2, 6), 64, 0, stream>>>(convW, Wf);
    k_embed<<<(NN + 3) / 4, 256, 0, stream>>>(an, emb, nucW, nucB, x0, xh);
    k_hist<<<(EE + 255) / 256, 256, 0, stream>>>(dstI, counts);
    const int NB = (NN + 1023) / 1024;
    k_scan_local<<<NB, 1024, 0, stream>>>(counts, rp, bsum);
    k_scan_off<<<1, 64, 0, stream>>>(bsum, NB);
    k_scan_add<<<NB, 1024, 0, stream>>>(rp, bsum);
    k_wsn<<<SW / 256, 256, 0, stream>>>(rp, wsn);
    k_scatter<<<(EE + 255) / 256, 256, 0, stream>>>(srcI, dstI, dist, rp, cursor, ej);
    k_gp<<<1, 128, 0, stream>>>(batch, gp);

    float* xin = x0;
    float* xout = x1;
    const __half2* up = (const __half2*)uph;
    const __half2* vp = (const __half2*)vph;
    const int UVB = (NN / 16 + 3) / 4;
    for (int l = 0; l < 6; l++) {
        if (l == 0) {
            k_uvmm<<<UVB, 256, 0, stream>>>(xh, Wf, 0, uph, vph);
        } else {
            k_uvln2<<<UVB, 256, 0, stream>>>(accb, lng, lnb, l - 1,
                                             xin, xout, Wf, l, uph, vph);
            float* tmp = xin; xin = xout; xout = tmp;  // xin = x_l
        }
        const __half2* Tnl = Tall + (size_t)l * TS * 64;
        float* sums = sums6 + (size_t)l * 256;
        if (l == 3) {
            // A/B probe: fp8 full-row stats with HW cvt on this layer only
            k_v8<<<(NN * 32 + 255) / 256, 256, 0, stream>>>(vph, vp8);
            const unsigned* Tnl8 = (const unsigned*)(Tall8 + (size_t)l * TS * 64);
            k_stats8b<<<1024, 256, 0, stream>>>(up, vp8, Tnl8, ej, rp, wsn, sums);
        } else {
            k_stats_h<<<2048, 256, 0, stream>>>(up, vp, Tnl, ej, rp, wsn, sums);
        }
        k_aggh<<<10000, 256, 0, stream>>>(up, vp, Tnl, ej, rp, sums,
                                          bng, bnb, l, accb);
    }
    // final layer epilogue
    k_lnfin<<<NN / 4, 256, 0, stream>>>(accb, lng, lnb, 5, xin, xout);
    k_pool2<<<GG, 256, 0, stream>>>(xout, gp, mols);
    k_mlp<<<GG, 128, 0, stream>>>(mols, fc1W, fc1b, fcsW, fcsb, outW, outb, (float*)d_out);
}

// Round 11
// 742.885 us; speedup vs baseline: 1.0371x; 1.0371x over previous
//
#include <hip/hip_runtime.h>
#include <hip/hip_fp16.h>
#include <cmath>

#define NN 20000
#define EE 500000
#define GG 64
#define TS 8192
#define SW 4096   // edge-balanced wave count (per stats half-kernel)
#define EPS 1e-5f
#define LOG2E 1.442695040888963f
#define LN2 0.693147180559945f

typedef unsigned long long u64a __attribute__((aligned(4)));
typedef _Float16 f16x8 __attribute__((ext_vector_type(8)));
typedef float f32x4 __attribute__((ext_vector_type(4)));

__device__ __forceinline__ float softplus_ref(float x) {
    return fmaxf(x, 0.f) + log1pf(__expf(-fabsf(x)));
}

// gaussian table: g[s][k] = exp(coeff*(d_s - o_k)^2)
__global__ void k_gtab(float* __restrict__ g) {
    int i = blockIdx.x * 256 + threadIdx.x;
    if (i >= TS * 100) return;
    int s = i / 100, k = i - 100 * s;
    float d = s * (6.0f / (TS - 1.0f));
    float o = k * (6.0f / 99.0f);
    float step = 6.0f / 99.0f;
    float coeff = -0.5f / (step * step);
    float df = d - o;
    g[i] = __expf(coeff * df * df);
}

// Nearest-neighbor table, paired channels: Tn[l][s][t] = half2(T[c=t], T[c=t+64])
__global__ void __launch_bounds__(256) k_build_T(
    const float* __restrict__ g, const float* __restrict__ convW,
    const float* __restrict__ convB, __half2* __restrict__ Tn) {
    int lane = threadIdx.x & 63;
    int wv = __builtin_amdgcn_readfirstlane(threadIdx.x >> 6);
    int l = blockIdx.y;
    int s0 = blockIdx.x * 16 + wv * 4;
    const float* w = convW + ((size_t)l * 228 + 128) * 128;
    const float* g0 = g + (size_t)s0 * 100;
    float b0 = convB[l * 128 + lane], b1 = convB[l * 128 + lane + 64];
    float2 a0 = {b0, b1}, a1 = {b0, b1}, a2 = {b0, b1}, a3 = {b0, b1};
#pragma unroll 4
    for (int k = 0; k < 100; k++) {
        float w0 = w[k * 128 + lane];
        float w1 = w[k * 128 + lane + 64];
        float ga = g0[k], gb = g0[100 + k], gc = g0[200 + k], gd = g0[300 + k];
        a0.x += ga * w0; a0.y += ga * w1;
        a1.x += gb * w0; a1.y += gb * w1;
        a2.x += gc * w0; a2.y += gc * w1;
        a3.x += gd * w0; a3.y += gd * w1;
    }
    Tn[((size_t)l * TS + s0 + 0) * 64 + lane] = __floats2half2_rn(a0.x, a0.y);
    Tn[((size_t)l * TS + s0 + 1) * 64 + lane] = __floats2half2_rn(a1.x, a1.y);
    Tn[((size_t)l * TS + s0 + 2) * 64 + lane] = __floats2half2_rn(a2.x, a2.y);
    Tn[((size_t)l * TS + s0 + 3) * 64 + lane] = __floats2half2_rn(a3.x, a3.y);
}

// W fragments for mfma_f32_16x16x32_f16, B operand, output-col permuted so the
// natural store order IS the (c, c+64) pair layout of uph/vph.
__global__ void k_prepW2(const float* __restrict__ convW, _Float16* __restrict__ Wf) {
    int lane = threadIdx.x;   // 64
    int ct = blockIdx.x;      // 16
    int half = blockIdx.y;    // 2
    int l = blockIdx.z;       // 6
    int p = ct * 16 + (lane & 15);
    int s = p >> 7;           // 0 = u block (W rows 0..63), 1 = v block (rows 64..127)
    int r = p & 127;
    int colW = (r >> 1) + (r & 1) * 64;
    int k0 = half * 32 + (lane >> 4) * 8;
    _Float16* dst = Wf + (((size_t)(l * 16 + ct) * 2 + half) * 64 + lane) * 8;
#pragma unroll
    for (int i = 0; i < 8; i++) {
        float v = convW[((size_t)l * 228 + s * 64 + k0 + i) * 128 + colW];
        dst[i] = (_Float16)v;
    }
}

__global__ void k_embed(const int* __restrict__ an, const float* __restrict__ emb,
                        const float* __restrict__ W, const float* __restrict__ b,
                        float* __restrict__ x, _Float16* __restrict__ xh) {
    int c = threadIdx.x & 63, nl = threadIdx.x >> 6;
    int n = blockIdx.x * 4 + nl;
    if (n >= NN) return;
    const float* e = emb + (size_t)an[n] * 92;
    float acc = b[c];
#pragma unroll 4
    for (int k = 0; k < 92; k++) acc += e[k] * W[k * 64 + c];
    x[(size_t)n * 64 + c] = acc;
    xh[(size_t)n * 64 + c] = (_Float16)acc;
}

__global__ void k_hist(const int* __restrict__ dst, int* __restrict__ counts) {
    int e = blockIdx.x * 256 + threadIdx.x;
    if (e < EE) atomicAdd(&counts[dst[e]], 1);
}

__global__ void k_scan_local(const int* __restrict__ counts, int* __restrict__ rp,
                             int* __restrict__ bsum) {
    __shared__ int buf[1024];
    int b = blockIdx.x, tid = threadIdx.x;
    int i = b * 1024 + tid;
    int val = (i < NN) ? counts[i] : 0;
    buf[tid] = val;
    __syncthreads();
    for (int off = 1; off < 1024; off <<= 1) {
        int t = (tid >= off) ? buf[tid - off] : 0;
        __syncthreads();
        buf[tid] += t;
        __syncthreads();
    }
    if (i < NN) rp[i + 1] = buf[tid];
    if (tid == 1023) bsum[b] = buf[1023];
}

__global__ void k_scan_off(int* __restrict__ bsum, int nb) {
    if (threadIdx.x == 0) {
        int acc = 0;
        for (int b = 0; b < nb; b++) { int v = bsum[b]; bsum[b] = acc; acc += v; }
    }
}

__global__ void k_scan_add(int* __restrict__ rp, const int* __restrict__ bsum) {
    int b = blockIdx.x, tid = threadIdx.x;
    int i = b * 1024 + tid;
    if (i < NN) rp[i + 1] += bsum[b];
    if (b == 0 && tid == 0) rp[0] = 0;
}

// wave -> start node for edge-balanced stats kernels
__global__ void k_wsn(const int* __restrict__ rp, int* __restrict__ wsn) {
    int w = blockIdx.x * 256 + threadIdx.x;
    if (w >= SW) return;
    int e0 = (int)((long long)w * EE / SW);
    int lo = 0, hi = NN;
    while (lo + 1 < hi) {
        int mid = (lo + hi) >> 1;
        if (rp[mid] <= e0) lo = mid; else hi = mid;
    }
    wsn[w] = lo;
}

// scatter + pack fused: ej[pos] = (src<<13) | j  (dst-sorted order)
__global__ void k_scatter(const int* __restrict__ src, const int* __restrict__ dst,
                          const float* __restrict__ dist, const int* __restrict__ rp,
                          int* __restrict__ cursor, unsigned* __restrict__ ej) {
    int e = blockIdx.x * 256 + threadIdx.x;
    if (e < EE) {
        int d = dst[e];
        int p = atomicAdd(&cursor[d], 1);
        float t = dist[e] * ((TS - 1.0f) / 6.0f);
        int j = (int)(t + 0.5f);
        if (j > TS - 1) j = TS - 1;
        ej[rp[d] + p] = ((unsigned)src[e] << 13) | (unsigned)j;
    }
}

// u,v via MFMA (layer 0): [20000x64]x[64x256] fp16 GEMM, fp32 accum.
__global__ void __launch_bounds__(256) k_uvmm(
    const _Float16* __restrict__ xh, const _Float16* __restrict__ Wf, int l,
    _Float16* __restrict__ uph, _Float16* __restrict__ vph) {
    int lane = threadIdx.x & 63;
    int wv = threadIdx.x >> 6;
    int tile = blockIdx.x * 4 + wv;
    if (tile >= NN / 16) return;
    int node = tile * 16 + (lane & 15);
    const f16x8* ax = (const f16x8*)(xh + (size_t)node * 64 + ((lane >> 4) * 8));
    f16x8 a0 = ax[0];   // k 0..31 slice
    f16x8 a1 = ax[4];   // k 32..63 slice
    const f16x8* wf = (const f16x8*)Wf + (size_t)l * 16 * 2 * 64;
    int rowb = tile * 16 + ((lane >> 4) << 2);
#pragma unroll
    for (int ct = 0; ct < 16; ct++) {
        f16x8 b0 = wf[(ct * 2 + 0) * 64 + lane];
        f16x8 b1 = wf[(ct * 2 + 1) * 64 + lane];
        f32x4 acc = {0.f, 0.f, 0.f, 0.f};
        acc = __builtin_amdgcn_mfma_f32_16x16x32_f16(a0, b0, acc, 0, 0, 0);
        acc = __builtin_amdgcn_mfma_f32_16x16x32_f16(a1, b1, acc, 0, 0, 0);
        int p = ct * 16 + (lane & 15);
        _Float16* dst = (p < 128) ? (uph + p) : (vph + (p - 128));
#pragma unroll
        for (int r2 = 0; r2 < 4; r2++)
            dst[(size_t)(rowb + r2) * 128] = (_Float16)acc[r2];
    }
}

// Fused LN(prev)+residual+softplus in fragment layout, then MFMA u,v (layers 1..5).
__global__ void __launch_bounds__(256) k_uvln2(
    const float* __restrict__ accb, const float* __restrict__ lng,
    const float* __restrict__ lnb, int lp,
    const float* __restrict__ xin, float* __restrict__ xout,
    const _Float16* __restrict__ Wf, int l,
    _Float16* __restrict__ uph, _Float16* __restrict__ vph) {
    int lane = threadIdx.x & 63;
    int wv = threadIdx.x >> 6;
    int tile = blockIdx.x * 4 + wv;
    if (tile >= NN / 16) return;
    int node = tile * 16 + (lane & 15);
    int ks = (lane >> 4) * 8;
    const float* ab = accb + (size_t)node * 64;
    const float* xb = xin + (size_t)node * 64;
    float av[16], xr[16];
#pragma unroll
    for (int i = 0; i < 8; i++) { av[i] = ab[ks + i]; av[8 + i] = ab[32 + ks + i]; }
#pragma unroll
    for (int i = 0; i < 8; i++) { xr[i] = xb[ks + i]; xr[8 + i] = xb[32 + ks + i]; }
    float s = 0.f;
#pragma unroll
    for (int i = 0; i < 16; i++) s += av[i];
    s += __shfl_xor(s, 16, 64);
    s += __shfl_xor(s, 32, 64);
    float mean = s * (1.0f / 64.0f);
    float vv = 0.f;
#pragma unroll
    for (int i = 0; i < 16; i++) { float d = av[i] - mean; vv += d * d; }
    vv += __shfl_xor(vv, 16, 64);
    vv += __shfl_xor(vv, 32, 64);
    float rs = rsqrtf(vv * (1.0f / 64.0f) + EPS);
    const float* lg = lng + lp * 64;
    const float* lb = lnb + lp * 64;
    f16x8 a0, a1;
    float* xo = xout + (size_t)node * 64;
#pragma unroll
    for (int i = 0; i < 8; i++) {
        float h = (av[i] - mean) * rs * lg[ks + i] + lb[ks + i];
        float o = softplus_ref(h + xr[i]);
        xo[ks + i] = o;
        a0[i] = (_Float16)o;
    }
#pragma unroll
    for (int i = 0; i < 8; i++) {
        float h = (av[8 + i] - mean) * rs * lg[32 + ks + i] + lb[32 + ks + i];
        float o = softplus_ref(h + xr[8 + i]);
        xo[32 + ks + i] = o;
        a1[i] = (_Float16)o;
    }
    const f16x8* wf = (const f16x8*)Wf + (size_t)l * 16 * 2 * 64;
    int rowb = tile * 16 + ((lane >> 4) << 2);
#pragma unroll
    for (int ct = 0; ct < 16; ct++) {
        f16x8 b0 = wf[(ct * 2 + 0) * 64 + lane];
        f16x8 b1 = wf[(ct * 2 + 1) * 64 + lane];
        f32x4 acc = {0.f, 0.f, 0.f, 0.f};
        acc = __builtin_amdgcn_mfma_f32_16x16x32_f16(a0, b0, acc, 0, 0, 0);
        acc = __builtin_amdgcn_mfma_f32_16x16x32_f16(a1, b1, acc, 0, 0, 0);
        int p = ct * 16 + (lane & 15);
        _Float16* dst = (p < 128) ? (uph + p) : (vph + (p - 128));
#pragma unroll
        for (int r2 = 0; r2 < 4; r2++)
            dst[(size_t)(rowb + r2) * 128] = (_Float16)acc[r2];
    }
}

// ---------------- fp16 half-row gather machinery ----------------
#define GRP2(P, BODY)                                                        \
    {                                                                        \
        unsigned e[P];                                                       \
        _Pragma("unroll")                                                    \
        for (int t = 0; t < P; t++) {                                        \
            unsigned long long ep = *(const u64a*)&ej[idx + 2 * t];          \
            e[t] = slot ? (unsigned)(ep >> 32) : (unsigned)ep;               \
        }                                                                    \
        __half2 vh[P], th[P];                                                \
        _Pragma("unroll")                                                    \
        for (int t = 0; t < P; t++) {                                        \
            vh[t] = vp[(size_t)(e[t] >> 13) * 64 + hp];                      \
            th[t] = Tn[(size_t)(e[t] & 8191u) * 64 + hp];                    \
        }                                                                    \
        _Pragma("unroll")                                                    \
        for (int t = 0; t < P; t++) { BODY }                                 \
    }

#define STATS_BODY                                                           \
    float2 vv = __half22float2(vh[t]);                                       \
    float2 tt = __half22float2(th[t]);                                       \
    float z0 = uu.x + vv.x + tt.x;                                           \
    float z1 = uu.y + vv.y + tt.y;                                           \
    sx += z0; qx += z0 * z0; sy += z1; qy += z1 * z1;

#define AGG_BODY                                                             \
    __half2 vt = __hadd2(vh[t], th[t]);                                      \
    float2 f = __half22float2(vt);                                           \
    float z0 = fmaf(A1, f.x, C1);                                            \
    float z1 = fmaf(A2, f.y, C2);                                            \
    float sg = __builtin_amdgcn_rcpf(1.0f + __builtin_amdgcn_exp2f(-z0));    \
    float sp = fmaxf(z1, 0.f) +                                              \
               __builtin_amdgcn_logf(1.0f + __builtin_amdgcn_exp2f(-fabsf(z1))); \
    acc += sg * sp;

// pass A (fp16): BN stats; channel-half pinned to XCD group via blockIdx%8.
__global__ void __launch_bounds__(256) k_stats_h(
    const __half2* __restrict__ up, const __half2* __restrict__ vp,
    const __half2* __restrict__ Tn, const unsigned* __restrict__ ej,
    const int* __restrict__ rp, const int* __restrict__ wsn,
    float* __restrict__ sums) {
    int lane = threadIdx.x & 63;
    int wv = __builtin_amdgcn_readfirstlane(threadIdx.x >> 6);
    int bid = blockIdx.x;
    int h = (bid >> 2) & 1;
    int r = ((bid >> 3) << 2) | (bid & 3);
    int slot = lane >> 5;
    int hp = h * 32 + (lane & 31);
    int w = r * 4 + wv;
    int e0 = (int)((long long)w * EE / SW);
    int e1 = (int)((long long)(w + 1) * EE / SW);
    int n = __builtin_amdgcn_readfirstlane(wsn[w]);
    int rend = __builtin_amdgcn_readfirstlane(rp[n + 1]);
    float sx = 0.f, sy = 0.f, qx = 0.f, qy = 0.f;
    int idx = e0;
    while (idx < e1) {
        while (idx >= rend) {
            ++n;
            rend = __builtin_amdgcn_readfirstlane(rp[n + 1]);
        }
        float2 uu = __half22float2(up[(size_t)n * 64 + hp]);
        int stop = (e1 < rend) ? e1 : rend;
        for (; idx + 16 <= stop; idx += 16) GRP2(8, STATS_BODY)
        if (idx + 8 <= stop) { GRP2(4, STATS_BODY) idx += 8; }
        if (idx + 4 <= stop) { GRP2(2, STATS_BODY) idx += 4; }
        if (idx + 2 <= stop) { GRP2(1, STATS_BODY) idx += 2; }
        if (idx < stop) {
            unsigned e = ej[idx];
            __half2 vh0 = vp[(size_t)(e >> 13) * 64 + hp];
            __half2 th0 = Tn[(size_t)(e & 8191u) * 64 + hp];
            float2 vv = __half22float2(vh0);
            float2 tt = __half22float2(th0);
            float z0 = uu.x + vv.x + tt.x;
            float z1 = uu.y + vv.y + tt.y;
            if (!slot) {
                sx += z0; qx += z0 * z0; sy += z1; qy += z1 * z1;
            }
            idx += 1;
        }
    }
    sx += __shfl_xor(sx, 32, 64); sy += __shfl_xor(sy, 32, 64);
    qx += __shfl_xor(qx, 32, 64); qy += __shfl_xor(qy, 32, 64);
    __shared__ float red[4][32][4];
    if (!slot) {
        float* rr = red[wv][lane & 31];
        rr[0] = sx; rr[1] = sy; rr[2] = qx; rr[3] = qy;
    }
    __syncthreads();
    if (wv == 0 && !slot) {
        for (int q = 1; q < 4; q++) {
            const float* rr = red[q][lane & 31];
            sx += rr[0]; sy += rr[1]; qx += rr[2]; qy += rr[3];
        }
        int c0 = hp;
        atomicAdd(&sums[c0], sx);
        atomicAdd(&sums[64 + c0], sy);
        atomicAdd(&sums[128 + c0], qx);
        atomicAdd(&sums[192 + c0], qy);
    }
}

// pass B: half-channel aggregate; writes partial acc (no LN here).
__global__ void __launch_bounds__(256) k_aggh(
    const __half2* __restrict__ up, const __half2* __restrict__ vp,
    const __half2* __restrict__ Tn, const unsigned* __restrict__ ej,
    const int* __restrict__ rp, const float* __restrict__ sums,
    const float* __restrict__ bng, const float* __restrict__ bnb,
    int l, float* __restrict__ accbuf) {
    int lane = threadIdx.x & 63;
    int wv = __builtin_amdgcn_readfirstlane(threadIdx.x >> 6);
    int bid = blockIdx.x;
    int h = (bid >> 2) & 1;
    int r = ((bid >> 3) << 2) | (bid & 3);
    int slot = lane >> 5;
    int hp = h * 32 + (lane & 31);
    int i = r * 4 + wv;

    int c0 = hp;
    float mu1 = sums[c0] * (1.0f / EE);
    float var1 = sums[128 + c0] * (1.0f / EE) - mu1 * mu1;
    float A1 = rsqrtf(var1 + EPS) * bng[l * 128 + c0];
    float B1 = bnb[l * 128 + c0] - mu1 * A1;
    float mu2 = sums[64 + c0] * (1.0f / EE);
    float var2 = sums[192 + c0] * (1.0f / EE) - mu2 * mu2;
    float A2 = rsqrtf(var2 + EPS) * bng[l * 128 + 64 + c0];
    float B2 = bnb[l * 128 + 64 + c0] - mu2 * A2;

    float2 uu = __half22float2(up[(size_t)i * 64 + hp]);
    float C1 = fmaf(A1, uu.x, B1) * LOG2E;
    float C2 = fmaf(A2, uu.y, B2) * LOG2E;
    A1 *= LOG2E; A2 *= LOG2E;
    float acc = 0.f;
    int rs = __builtin_amdgcn_readfirstlane(rp[i]);
    int re = __builtin_amdgcn_readfirstlane(rp[i + 1]);
    int idx = rs;
    for (; idx + 16 <= re; idx += 16) GRP2(8, AGG_BODY)
    if (idx + 8 <= re) { GRP2(4, AGG_BODY) idx += 8; }
    if (idx + 4 <= re) { GRP2(2, AGG_BODY) idx += 4; }
    if (idx + 2 <= re) { GRP2(1, AGG_BODY) idx += 2; }
    if (idx < re) {
        unsigned e = ej[idx];
        __half2 vh0 = vp[(size_t)(e >> 13) * 64 + hp];
        __half2 th0 = Tn[(size_t)(e & 8191u) * 64 + hp];
        __half2 vt = __hadd2(vh0, th0);
        float2 f = __half22float2(vt);
        float z0 = fmaf(A1, f.x, C1);
        float z1 = fmaf(A2, f.y, C2);
        float sg = __builtin_amdgcn_rcpf(1.0f + __builtin_amdgcn_exp2f(-z0));
        float sp = fmaxf(z1, 0.f) +
                   __builtin_amdgcn_logf(1.0f + __builtin_amdgcn_exp2f(-fabsf(z1)));
        if (!slot) acc += sg * sp;
    }
    acc += __shfl_xor(acc, 32, 64);
    if (!slot) accbuf[(size_t)i * 64 + hp] = acc * LN2;
}

// final-layer LN + residual + softplus epilogue
__global__ void __launch_bounds__(256) k_lnfin(
    const float* __restrict__ accbuf,
    const float* __restrict__ lng, const float* __restrict__ lnb,
    int l, const float* __restrict__ xin, float* __restrict__ xout) {
    int lane = threadIdx.x & 63;
    int wv = __builtin_amdgcn_readfirstlane(threadIdx.x >> 6);
    int i = blockIdx.x * 4 + wv;
    float a = accbuf[(size_t)i * 64 + lane];
    float xr = xin[(size_t)i * 64 + lane];
    float s = a;
#pragma unroll
    for (int off = 32; off; off >>= 1) s += __shfl_xor(s, off, 64);
    float mean = s * (1.0f / 64.0f);
    float e0v = a - mean;
    float vv2 = e0v * e0v;
#pragma unroll
    for (int off = 32; off; off >>= 1) vv2 += __shfl_xor(vv2, off, 64);
    float var = vv2 * (1.0f / 64.0f);
    float h = e0v * rsqrtf(var + EPS) * lng[l * 64 + lane] + lnb[l * 64 + lane];
    xout[(size_t)i * 64 + lane] = softplus_ref(h + xr);
}

// batch sorted -> graph row pointers by binary search
__global__ void k_gp(const int* __restrict__ batch, int* __restrict__ gp) {
    int g = threadIdx.x;
    if (g > GG) return;
    int lo = 0, hi = NN;
    while (lo < hi) {
        int mid = (lo + hi) >> 1;
        if (batch[mid] < g) lo = mid + 1; else hi = mid;
    }
    gp[g] = lo;
}

// atomic-free segmented mean-pool
__global__ void k_pool2(const float* __restrict__ x, const int* __restrict__ gp,
                        float* __restrict__ mols) {
    int g = blockIdx.x;
    int lane = threadIdx.x & 63, slot = threadIdx.x >> 6;
    int s0 = gp[g], s1 = gp[g + 1];
    float acc = 0.f;
    for (int n = s0 + slot; n < s1; n += 4) acc += x[(size_t)n * 64 + lane];
    __shared__ float red[4][64];
    red[slot][lane] = acc;
    __syncthreads();
    if (slot == 0) {
        float a = red[0][lane] + red[1][lane] + red[2][lane] + red[3][lane];
        float cc = fmaxf((float)(s1 - s0), 1.0f);
        mols[g * 64 + lane] = a / cc;
    }
}

__global__ void k_mlp(const float* __restrict__ mols,
                      const float* __restrict__ fc1W, const float* __restrict__ fc1b,
                      const float* __restrict__ fcsW, const float* __restrict__ fcsb,
                      const float* __restrict__ outW, const float* __restrict__ outb,
                      float* __restrict__ y) {
    int g = blockIdx.x, t = threadIdx.x; // 128 threads
    __shared__ float m[64];
    __shared__ float h[128];
    __shared__ float rbuf[128];
    if (t < 64) m[t] = mols[g * 64 + t];
    __syncthreads();
    float a = fc1b[t];
#pragma unroll 16
    for (int k = 0; k < 64; k++) a += m[k] * fc1W[k * 128 + t];
    h[t] = softplus_ref(a);
    __syncthreads();
    for (int i = 0; i < 3; i++) {
        float b = fcsb[i * 128 + t];
#pragma unroll 16
        for (int k = 0; k < 128; k++) b += h[k] * fcsW[((size_t)i * 128 + k) * 128 + t];
        __syncthreads();
        h[t] = softplus_ref(b);
        __syncthreads();
    }
    rbuf[t] = h[t] * outW[t];
    __syncthreads();
    if (t < 64) {
        float s2 = rbuf[t] + rbuf[t + 64];
#pragma unroll
        for (int off = 32; off; off >>= 1) s2 += __shfl_xor(s2, off, 64);
        if (t == 0) y[g] = s2 + outb[0];
    }
}

extern "C" void kernel_launch(void* const* d_in, const int* in_sizes, int n_in,
                              void* d_out, int out_size, void* d_ws, size_t ws_size,
                              hipStream_t stream) {
    const int*   an    = (const int*)d_in[0];
    const int*   nbr   = (const int*)d_in[1];
    const float* dist  = (const float*)d_in[2];
    const int*   batch = (const int*)d_in[3];
    const float* emb   = (const float*)d_in[4];
    const float* nucW  = (const float*)d_in[5];
    const float* nucB  = (const float*)d_in[6];
    const float* convW = (const float*)d_in[7];
    const float* convB = (const float*)d_in[8];
    const float* bng   = (const float*)d_in[9];
    const float* bnb   = (const float*)d_in[10];
    const float* lng   = (const float*)d_in[11];
    const float* lnb   = (const float*)d_in[12];
    const float* fc1W  = (const float*)d_in[13];
    const float* fc1b  = (const float*)d_in[14];
    const float* fcsW  = (const float*)d_in[15];
    const float* fcsb  = (const float*)d_in[16];
    const float* outW  = (const float*)d_in[17];
    const float* outb  = (const float*)d_in[18];
    const int* srcI = nbr;
    const int* dstI = nbr + EE;

    char* base = (char*)d_ws;
    size_t off = 0;
    auto alloc = [&](size_t b) { size_t r = off; off += (b + 255) & ~(size_t)255; return r; };
    float*     gtab   = (float*)(base + alloc((size_t)TS * 100 * 4));
    __half2*   Tall   = (__half2*)(base + alloc((size_t)6 * TS * 64 * 4));
    _Float16*  Wf     = (_Float16*)(base + alloc((size_t)6 * 16 * 2 * 64 * 8 * 2));
    float*     x0     = (float*)(base + alloc((size_t)NN * 64 * 4));
    float*     x1     = (float*)(base + alloc((size_t)NN * 64 * 4));
    _Float16*  xh     = (_Float16*)(base + alloc((size_t)NN * 64 * 2));
    _Float16*  uph    = (_Float16*)(base + alloc((size_t)NN * 128 * 2));
    _Float16*  vph    = (_Float16*)(base + alloc((size_t)NN * 128 * 2));
    float*     accb   = (float*)(base + alloc((size_t)NN * 64 * 4));
    float*     sums6  = (float*)(base + alloc((size_t)6 * 256 * 4));
    int*       counts = (int*)(base + alloc((size_t)NN * 4));
    int*       cursor = (int*)(base + alloc((size_t)NN * 4));
    int*       rp     = (int*)(base + alloc((size_t)(NN + 1) * 4));
    int*       bsum   = (int*)(base + alloc(64 * 4));
    unsigned*  ej     = (unsigned*)(base + alloc((size_t)(EE + 64) * 4));
    int*       wsn    = (int*)(base + alloc((size_t)SW * 4));
    float*     mols   = (float*)(base + alloc((size_t)GG * 64 * 4));
    int*       gp     = (int*)(base + alloc((size_t)(GG + 1) * 4));

    hipMemsetAsync(counts, 0, (size_t)NN * 4, stream);
    hipMemsetAsync(cursor, 0, (size_t)NN * 4, stream);
    hipMemsetAsync(sums6, 0, (size_t)6 * 256 * 4, stream);

    k_gtab<<<(TS * 100 + 255) / 256, 256, 0, stream>>>(gtab);
    k_build_T<<<dim3(TS / 16, 6), 256, 0, stream>>>(gtab, convW, convB, Tall);
    k_prepW2<<<dim3(16, 2, 6), 64, 0, stream>>>(convW, Wf);
    k_embed<<<(NN + 3) / 4, 256, 0, stream>>>(an, emb, nucW, nucB, x0, xh);
    k_hist<<<(EE + 255) / 256, 256, 0, stream>>>(dstI, counts);
    const int NB = (NN + 1023) / 1024;
    k_scan_local<<<NB, 1024, 0, stream>>>(counts, rp, bsum);
    k_scan_off<<<1, 64, 0, stream>>>(bsum, NB);
    k_scan_add<<<NB, 1024, 0, stream>>>(rp, bsum);
    k_wsn<<<SW / 256, 256, 0, stream>>>(rp, wsn);
    k_scatter<<<(EE + 255) / 256, 256, 0, stream>>>(srcI, dstI, dist, rp, cursor, ej);
    k_gp<<<1, 128, 0, stream>>>(batch, gp);

    float* xin = x0;
    float* xout = x1;
    const __half2* up = (const __half2*)uph;
    const __half2* vp = (const __half2*)vph;
    const int UVB = (NN / 16 + 3) / 4;
    for (int l = 0; l < 6; l++) {
        if (l == 0) {
            k_uvmm<<<UVB, 256, 0, stream>>>(xh, Wf, 0, uph, vph);
        } else {
            k_uvln2<<<UVB, 256, 0, stream>>>(accb, lng, lnb, l - 1,
                                             xin, xout, Wf, l, uph, vph);
            float* tmp = xin; xin = xout; xout = tmp;  // xin = x_l
        }
        const __half2* Tnl = Tall + (size_t)l * TS * 64;
        float* sums = sums6 + (size_t)l * 256;
        k_stats_h<<<2048, 256, 0, stream>>>(up, vp, Tnl, ej, rp, wsn, sums);
        k_aggh<<<10000, 256, 0, stream>>>(up, vp, Tnl, ej, rp, sums,
                                          bng, bnb, l, accb);
    }
    // final layer epilogue
    k_lnfin<<<NN / 4, 256, 0, stream>>>(accb, lng, lnb, 5, xin, xout);
    k_pool2<<<GG, 256, 0, stream>>>(xout, gp, mols);
    k_mlp<<<GG, 128, 0, stream>>>(mols, fc1W, fc1b, fcsW, fcsb, outW, outb, (float*)d_out);
}